// Round 5
// baseline (739.178 us; speedup 1.0000x reference)
//
#include <hip/hip_runtime.h>
#include <hip/hip_cooperative_groups.h>
#include <math.h>

namespace cg = cooperative_groups;

#define NPED 512
#define NBLK 256          // 2 peds per block; grid == #CUs so cooperative launch always validates
#define OBS 8
#define PRED 12
#define HE 8
#define HD 16
#define EMB 16
#define NZ 8
#define NSEQ 8

// global ws layout (floats): double-buffered pos + HB by t-parity
#define WS_POS0 0
#define WS_POS1 (NPED*2)
#define WS_HB0  (NPED*4)
#define WS_HB1  (WS_HB0 + NPED*64)

typedef const float* fp;

__device__ __forceinline__ float frcp(float x){ return __builtin_amdgcn_rcpf(x); }
__device__ __forceinline__ float sigm(float x){ return frcp(1.0f + __expf(-x)); }
__device__ __forceinline__ float tanh_f(float x){ return 1.0f - 2.0f*frcp(__expf(2.0f*x) + 1.0f); }
__device__ __forceinline__ void fma4(float4& a, const float4 w, float s){
    a.x += w.x*s; a.y += w.y*s; a.z += w.z*s; a.w += w.w*s;
}

struct Params {
    fp traj, obs, h0, c0, noise;
    fp Wenc, benc, Wdec, bdec;
    fp Wiht, Whht, biht, bhht;
    fp Wihp, Whhp, bihp, bhhp;
    fp Wout, bout, Wse, bse, Wm1, bm1, Wm2, bm2, Watt, batt;
    const int* sse; const int* nei;
    float* ws; float* out;
};

// one (i,j) pair: returns attention score s, fills pre[4] (relu'd m2 output)
__device__ __forceinline__ float pool_pair(
        int j, float pix, float piy,
        const float* s_posx, const float* s_posy,
        const float4* s_abb, const float4* s_wm2t,
        const float4* s_bm24, const float4* s_watt4, float batt,
        const float* hbbuf, float4 pre[4])
{
    float cx = pix - s_posx[j], cy = piy - s_posy[j];
    pre[0] = s_bm24[0]; pre[1] = s_bm24[1]; pre[2] = s_bm24[2]; pre[3] = s_bm24[3];
    const float4* HB4 = (const float4*)(hbbuf + j*64);
    #pragma unroll
    for (int uq = 0; uq < 16; uq++) {
        float4 hb = HB4[uq];
        #define DO_U(q_, comp_) { \
            float4 ab = s_abb[uq*4+q_]; \
            float h1 = fmaxf(ab.z + ab.x*cx + ab.y*cy + (comp_), 0.f); \
            const float4* wr = s_wm2t + (uq*4+q_)*4; \
            fma4(pre[0], wr[0], h1); fma4(pre[1], wr[1], h1); \
            fma4(pre[2], wr[2], h1); fma4(pre[3], wr[3], h1); }
        DO_U(0, hb.x) DO_U(1, hb.y) DO_U(2, hb.z) DO_U(3, hb.w)
        #undef DO_U
    }
    float s = batt;
    #pragma unroll
    for (int q = 0; q < 4; q++) {
        float4 v = pre[q];
        v.x = fmaxf(v.x,0.f); v.y = fmaxf(v.y,0.f); v.z = fmaxf(v.z,0.f); v.w = fmaxf(v.w,0.f);
        float4 wa = s_watt4[q];
        s += wa.x*v.x + wa.y*v.y + wa.z*v.z + wa.w*v.w;
        pre[q] = v;
    }
    return s;
}

__global__ __launch_bounds__(256, 2) void fused_kernel(Params p)
{
    __shared__ float s_wenc[32], s_benc[16], s_wihT[32*17], s_whhT[32*9], s_bT[32];
    __shared__ float s_wdec[16*19], s_bdec[16];
    __shared__ float s_wihP[64*17], s_whhP[64*17], s_wm1h[64*17], s_bP[64];
    __shared__ float s_wout[32], s_bout[2];
    __shared__ float4 s_abb[64], s_wm2t[256], s_bm24[4], s_watt4[4];
    __shared__ float s_batt;
    __shared__ float s_posx[NPED], s_posy[NPED];
    __shared__ int   s_list[NPED], s_cnt[8];
    __shared__ float s_red[4*17], s_mred[4];
    __shared__ float s_ctx[32], s_hc[32], s_pos[4];

    cg::grid_group grid = cg::this_grid();
    int tid = threadIdx.x;
    int n0 = blockIdx.x * 2;           // this block owns peds n0, n0+1

    // ---------------- one-time weight staging ----------------
    if (tid < 32) { s_wenc[tid] = p.Wenc[tid]; s_bT[tid] = p.biht[tid] + p.bhht[tid]; }
    if (tid < 16) { s_benc[tid] = p.benc[tid]; s_bdec[tid] = p.bdec[tid]; }
    for (int i = tid; i < 512; i += 256) s_wihT[(i>>4)*17 + (i&15)] = p.Wiht[i];
    { int i = tid; if (i < 256) s_whhT[(i>>3)*9 + (i&7)] = p.Whht[i]; }
    for (int i = tid; i < 288; i += 256) s_wdec[(i/18)*19 + (i%18)] = p.Wdec[i];
    for (int i = tid; i < 1024; i += 256) {
        int r = i>>4, d = i&15;
        s_wihP[r*17+d] = p.Wihp[i];
        s_whhP[r*17+d] = p.Whhp[i];
        s_wm1h[r*17+d] = p.Wm1[r*32 + 16 + d];
    }
    if (tid < 64) s_bP[tid] = p.bihp[tid] + p.bhhp[tid];
    if (tid < 32) s_wout[tid] = p.Wout[tid];
    if (tid < 2)  s_bout[tid] = p.bout[tid];
    if (tid < 64) {   // fold W_se/b_se into W_m1 -> A0,A1,bb per unit u
        float a0 = 0.f, a1 = 0.f, bb = p.bm1[tid];
        for (int kk = 0; kk < 16; kk++) {
            float w = p.Wm1[tid*32 + kk];
            a0 += w*p.Wse[kk*2+0]; a1 += w*p.Wse[kk*2+1]; bb += w*p.bse[kk];
        }
        s_abb[tid] = make_float4(a0, a1, bb, 0.f);
    }
    for (int i = tid; i < 1024; i += 256) {
        int u = i >> 4, v = i & 15;
        ((float*)s_wm2t)[u*16 + v] = p.Wm2[v*64 + u];
    }
    if (tid < 16) { ((float*)s_bm24)[tid] = p.bm2[tid]; ((float*)s_watt4)[tid] = p.Watt[tid]; }
    if (tid == 0) s_batt = p.batt[0];
    __syncthreads();

    // ---------------- encoder (lanes 0..15: pid = tid>>3, unit k = tid&7) ----
    if (tid < 16) {
        int pid = tid >> 3, k = tid & 7, n = n0 + pid;
        float h = p.h0[n*HE+k], c = p.c0[n*HE+k];
        for (int t = 0; t < OBS; t++) {
            float x0 = p.traj[(t*NPED+n)*2+0];
            float x1 = p.traj[(t*NPED+n)*2+1];
            float g0 = s_bT[k], g1 = s_bT[8+k], g2 = s_bT[16+k], g3 = s_bT[24+k];
            #pragma unroll
            for (int d = 0; d < EMB; d++) {
                float e = fmaxf(s_wenc[d*2]*x0 + s_wenc[d*2+1]*x1 + s_benc[d], 0.f);
                g0 += s_wihT[(k)*17+d]*e;  g1 += s_wihT[(8+k)*17+d]*e;
                g2 += s_wihT[(16+k)*17+d]*e; g3 += s_wihT[(24+k)*17+d]*e;
            }
            #pragma unroll
            for (int d = 0; d < HE; d++) {
                float hv = __shfl(h, d, 8);    // width 8: stays within this ped's lane group
                g0 += s_whhT[(k)*9+d]*hv;  g1 += s_whhT[(8+k)*9+d]*hv;
                g2 += s_whhT[(16+k)*9+d]*hv; g3 += s_whhT[(24+k)*9+d]*hv;
            }
            c = sigm(g1)*c + sigm(g0)*tanh_f(g2);
            h = sigm(g3)*tanh_f(c);
        }
        int cnt = 0;
        #pragma unroll
        for (int s2 = 0; s2 < NSEQ; s2++) cnt += (p.sse[s2*2] <= n) ? 1 : 0;
        s_hc[pid*16 + k] = h;
        s_hc[pid*16 + 8 + k] = p.noise[(cnt-1)*NZ + k];
    }
    if (tid < 4) { int pid = tid >> 1, k = tid & 1;
                   s_pos[pid*2+k] = p.obs[((OBS-1)*NPED + n0 + pid)*2 + k]; }
    if (tid < 32) s_ctx[tid] = 0.f;
    __syncthreads();

    float h = 0.f, c = 0.f;           // decoder state: lanes 0..31 (16 per ped)
    if (tid < 32) h = s_hc[tid];

    float* posB[2] = { p.ws + WS_POS0, p.ws + WS_POS1 };
    float* hbB[2]  = { p.ws + WS_HB0,  p.ws + WS_HB1  };
    int w = tid >> 6, lane = tid & 63;
    unsigned long long below = (1ull << lane) - 1ull;

    for (int t = 0; t < PRED; t++) {
        int par = t & 1;
        // ------------- step phase (lanes 0..31) -------------
        if (tid < 32) {
            int pid = tid >> 4, k = tid & 15, n = n0 + pid;
            float ctx = s_ctx[pid*16 + k];
            float o0 = 0.f, o1 = 0.f;
            if (t > 0) {
                float ch = ctx + h;
                float r0 = s_wout[k]*ch, r1 = s_wout[16+k]*ch;
                #pragma unroll
                for (int off = 8; off >= 1; off >>= 1) {
                    r0 += __shfl_xor(r0, off, 16);
                    r1 += __shfl_xor(r1, off, 16);
                }
                o0 = tanh_f(s_bout[0] + r0)*4.4f;
                o1 = tanh_f(s_bout[1] + r1)*4.4f;
                if (k < 2) {
                    float o = (k == 0) ? o0 : o1;
                    float np_ = s_pos[pid*2 + k] + o;
                    s_pos[pid*2 + k] = np_;
                    p.out[((t-1)*NPED + n)*2 + k] = o;
                    posB[par][n*2 + k] = np_;
                }
            } else {
                if (k < 2) posB[par][n*2 + k] = s_pos[pid*2 + k];
            }
            // e = relu(Wdec . [ctx, o0, o1])
            float e = s_bdec[k];
            #pragma unroll
            for (int d = 0; d < HD; d++) e += s_wdec[k*19 + d]*__shfl(ctx, d, 16);
            e += s_wdec[k*19+16]*o0 + s_wdec[k*19+17]*o1;
            e = fmaxf(e, 0.f);
            // LSTM
            float g0 = s_bP[k], g1 = s_bP[16+k], g2 = s_bP[32+k], g3 = s_bP[48+k];
            #pragma unroll
            for (int d = 0; d < HD; d++) {
                float ev = __shfl(e, d, 16);
                float hv = __shfl(h, d, 16);
                g0 += s_wihP[(k)*17+d]*ev    + s_whhP[(k)*17+d]*hv;
                g1 += s_wihP[(16+k)*17+d]*ev + s_whhP[(16+k)*17+d]*hv;
                g2 += s_wihP[(32+k)*17+d]*ev + s_whhP[(32+k)*17+d]*hv;
                g3 += s_wihP[(48+k)*17+d]*ev + s_whhP[(48+k)*17+d]*hv;
            }
            c = sigm(g1)*c + sigm(g0)*tanh_f(g2);
            h = sigm(g3)*tanh_f(c);
            // HB[n][u] = h . Wm1[u,16:32]
            float hb0=0.f, hb1=0.f, hb2=0.f, hb3=0.f;
            #pragma unroll
            for (int d = 0; d < HD; d++) {
                float hv = __shfl(h, d, 16);
                hb0 += s_wm1h[(k)*17+d]*hv;    hb1 += s_wm1h[(16+k)*17+d]*hv;
                hb2 += s_wm1h[(32+k)*17+d]*hv; hb3 += s_wm1h[(48+k)*17+d]*hv;
            }
            float* hb = hbB[par] + n*64;
            hb[k] = hb0; hb[16+k] = hb1; hb[32+k] = hb2; hb[48+k] = hb3;
        }

        grid.sync();   // all peds' HB/pos for step t visible grid-wide

        // ------------- pool phase (all 256 threads; two rows) -------------
        for (int j = tid; j < NPED; j += 256) {
            float2 pp = ((const float2*)posB[par])[j];
            s_posx[j] = pp.x; s_posy[j] = pp.y;
        }
        __syncthreads();

        for (int pid = 0; pid < 2; pid++) {
            int i = n0 + pid;
            const int* neirow = p.nei + ((size_t)t*NPED + i)*NPED;
            int a0 = neirow[tid]       > 0;
            int a1 = neirow[256 + tid] > 0;
            unsigned long long m0 = __ballot(a0), m1 = __ballot(a1);
            if (lane == 0) { s_cnt[w] = __popcll(m0); s_cnt[4+w] = __popcll(m1); }
            __syncthreads();
            int cnt = 0, base0 = 0, base1 = 0;
            #pragma unroll
            for (int q = 0; q < 8; q++) {
                int cq = s_cnt[q];
                cnt += cq;
                if (q < w)     base0 += cq;
                if (q < 4 + w) base1 += cq;
            }
            if (a0) s_list[base0 + __popcll(m0 & below)] = tid;
            if (a1) s_list[base1 + __popcll(m1 & below)] = 256 + tid;
            __syncthreads();

            float pix = s_posx[i], piy = s_posy[i];
            float4 z = make_float4(0.f,0.f,0.f,0.f);
            float4 preA[4] = {z,z,z,z}, preB[4] = {z,z,z,z};
            float sA = -INFINITY, sB = -INFINITY;
            if (tid < cnt)
                sA = pool_pair(s_list[tid], pix, piy, s_posx, s_posy,
                               s_abb, s_wm2t, s_bm24, s_watt4, s_batt, hbB[par], preA);
            if (256 + tid < cnt)
                sB = pool_pair(s_list[256+tid], pix, piy, s_posx, s_posy,
                               s_abb, s_wm2t, s_bm24, s_watt4, s_batt, hbB[par], preB);

            // pass 1: global max
            float mloc = fmaxf(sA, sB);
            #pragma unroll
            for (int off = 32; off >= 1; off >>= 1) mloc = fmaxf(mloc, __shfl_xor(mloc, off));
            if (lane == 0) s_mred[w] = mloc;
            __syncthreads();
            float M = fmaxf(fmaxf(s_mred[0], s_mred[1]), fmaxf(s_mred[2], s_mred[3]));

            // pass 2: rescaled sums
            if (cnt > 0) {
                float wA = __expf(sA - M), wB = __expf(sB - M);
                float l = wA + wB;
                float accv[16];
                const float* pa = (const float*)preA;
                const float* pb = (const float*)preB;
                #pragma unroll
                for (int v = 0; v < 16; v++) accv[v] = wA*pa[v] + wB*pb[v];
                #pragma unroll
                for (int off = 32; off >= 1; off >>= 1) {
                    l += __shfl_xor(l, off);
                    #pragma unroll
                    for (int v = 0; v < 16; v++) accv[v] += __shfl_xor(accv[v], off);
                }
                if (lane == 0) {
                    s_red[w*17] = l;
                    #pragma unroll
                    for (int v = 0; v < 16; v++) s_red[w*17 + 1 + v] = accv[v];
                }
            }
            __syncthreads();
            if (tid < 16) {
                float cv = 0.f;
                if (cnt > 0) {
                    float L = s_red[0] + s_red[17] + s_red[34] + s_red[51];
                    float a = s_red[1+tid] + s_red[17+1+tid] + s_red[34+1+tid] + s_red[51+1+tid];
                    cv = (L > 0.f) ? a / L : 0.f;
                }
                s_ctx[pid*16 + tid] = cv;
            }
            __syncthreads();
        }
    }

    // ---------------- final output (t = 11) ----------------
    if (tid < 32) {
        int pid = tid >> 4, k = tid & 15, n = n0 + pid;
        float ch = s_ctx[pid*16 + k] + h;
        float r0 = s_wout[k]*ch, r1 = s_wout[16+k]*ch;
        #pragma unroll
        for (int off = 8; off >= 1; off >>= 1) {
            r0 += __shfl_xor(r0, off, 16);
            r1 += __shfl_xor(r1, off, 16);
        }
        float o0 = tanh_f(s_bout[0] + r0)*4.4f;
        float o1 = tanh_f(s_bout[1] + r1)*4.4f;
        if (k == 0) p.out[((PRED-1)*NPED + n)*2 + 0] = o0;
        if (k == 1) p.out[((PRED-1)*NPED + n)*2 + 1] = o1;
    }
}

extern "C" void kernel_launch(void* const* d_in, const int* in_sizes, int n_in,
                              void* d_out, int out_size, void* d_ws, size_t ws_size,
                              hipStream_t stream)
{
    Params p;
    p.traj = (fp)d_in[0];
    p.obs  = (fp)d_in[1];
    p.h0   = (fp)d_in[3];
    p.c0   = (fp)d_in[4];
    p.noise= (fp)d_in[5];
    p.Wenc = (fp)d_in[6];  p.benc = (fp)d_in[7];
    p.Wdec = (fp)d_in[8];  p.bdec = (fp)d_in[9];
    p.Wiht = (fp)d_in[10]; p.Whht = (fp)d_in[11];
    p.biht = (fp)d_in[12]; p.bhht = (fp)d_in[13];
    p.Wihp = (fp)d_in[14]; p.Whhp = (fp)d_in[15];
    p.bihp = (fp)d_in[16]; p.bhhp = (fp)d_in[17];
    p.Wout = (fp)d_in[18]; p.bout = (fp)d_in[19];
    p.Wse  = (fp)d_in[20]; p.bse  = (fp)d_in[21];
    p.Wm1  = (fp)d_in[22]; p.bm1  = (fp)d_in[23];
    p.Wm2  = (fp)d_in[24]; p.bm2  = (fp)d_in[25];
    p.Watt = (fp)d_in[26]; p.batt = (fp)d_in[27];
    p.sse  = (const int*)d_in[28];
    p.nei  = (const int*)d_in[29];
    p.ws   = (float*)d_ws;
    p.out  = (float*)d_out;

    void* args[] = { &p };
    hipLaunchCooperativeKernel((const void*)fused_kernel, dim3(NBLK), dim3(256),
                               args, 0, stream);
}

// Round 6
// 291.804 us; speedup vs baseline: 2.5331x; 2.5331x over previous
//
#include <hip/hip_runtime.h>
#include <math.h>

#define NPED 512
#define OBS 8
#define PRED 12
#define HE 8
#define HD 16
#define EMB 16
#define NZ 8
#define NSEQ 8

typedef const float* fp;

__device__ __forceinline__ float frcp(float x){ return __builtin_amdgcn_rcpf(x); }
__device__ __forceinline__ float sigm(float x){ return frcp(1.0f + __expf(-x)); }
__device__ __forceinline__ float tanh_f(float x){ return 1.0f - 2.0f*frcp(__expf(2.0f*x) + 1.0f); }
__device__ __forceinline__ void fma4(float4& a, const float4 w, float s){
    a.x += w.x*s; a.y += w.y*s; a.z += w.z*s; a.w += w.w*s;
}

// ws layout (floats). h,c: block-private slots. pos,HB: parity double-buffered.
#define WS_H    0
#define WS_C    (WS_H + NPED*HD)
#define WS_POS0 (WS_C + NPED*HD)
#define WS_POS1 (WS_POS0 + NPED*2)
#define WS_HB0  (WS_POS1 + NPED*2)
#define WS_HB1  (WS_HB0 + NPED*64)

// ---------- init: encoder (8 lanes/ped) + decoder LSTM step 0 (16 lanes/ped)
__global__ __launch_bounds__(256) void init_kernel(
        fp traj, fp obs_pos, fp h0, fp c0, fp noise,
        fp Wenc, fp benc, fp Wih, fp Whh, fp bih, fp bhh,
        fp bdec, fp Wihp, fp Whhp, fp bihp, fp bhhp, fp Wm1,
        const int* sse, float* ws)
{
    __shared__ float s_wenc[32], s_benc[16], s_wihT[32*17], s_whhT[32*9], s_bT[32];
    __shared__ float s_wihP[64*17], s_whhP[64*17], s_wm1h[64*17], s_bP[64], s_e0[16];
    __shared__ float s_hc[16*16];
    int tid = threadIdx.x;
    if (tid < 32) { s_wenc[tid] = Wenc[tid]; s_bT[tid] = bih[tid] + bhh[tid]; }
    if (tid < 16) { s_benc[tid] = benc[tid]; s_e0[tid] = fmaxf(bdec[tid], 0.f); }
    for (int i = tid; i < 512; i += 256) s_wihT[(i>>4)*17 + (i&15)] = Wih[i];
    { int i = tid; if (i < 256) s_whhT[(i>>3)*9 + (i&7)] = Whh[i]; }
    for (int i = tid; i < 1024; i += 256) {
        int r = i>>4, d = i&15;
        s_wihP[r*17+d] = Wihp[i];
        s_whhP[r*17+d] = Whhp[i];
        s_wm1h[r*17+d] = Wm1[r*32 + 16 + d];
    }
    if (tid < 64) s_bP[tid] = bihp[tid] + bhhp[tid];
    __syncthreads();

    int pid = tid >> 4, k16 = tid & 15;
    int n = blockIdx.x*16 + pid;

    if (k16 < 8) {                       // encoder, 8 lanes per ped
        int k = k16;
        float h = h0[n*HE+k], c = c0[n*HE+k];
        for (int t = 0; t < OBS; t++) {
            float x0 = traj[(t*NPED+n)*2+0];
            float x1 = traj[(t*NPED+n)*2+1];
            float g0 = s_bT[k], g1 = s_bT[8+k], g2 = s_bT[16+k], g3 = s_bT[24+k];
            #pragma unroll
            for (int d = 0; d < EMB; d++) {
                float e = fmaxf(s_wenc[d*2]*x0 + s_wenc[d*2+1]*x1 + s_benc[d], 0.f);
                g0 += s_wihT[(k)*17+d]*e;    g1 += s_wihT[(8+k)*17+d]*e;
                g2 += s_wihT[(16+k)*17+d]*e; g3 += s_wihT[(24+k)*17+d]*e;
            }
            #pragma unroll
            for (int d = 0; d < HE; d++) {
                float hv = __shfl(h, d, 8);
                g0 += s_whhT[(k)*9+d]*hv;    g1 += s_whhT[(8+k)*9+d]*hv;
                g2 += s_whhT[(16+k)*9+d]*hv; g3 += s_whhT[(24+k)*9+d]*hv;
            }
            c = sigm(g1)*c + sigm(g0)*tanh_f(g2);
            h = sigm(g3)*tanh_f(c);
        }
        int cnt = 0;
        #pragma unroll
        for (int s2 = 0; s2 < NSEQ; s2++) cnt += (sse[s2*2] <= n) ? 1 : 0;
        s_hc[pid*16 + k]     = h;
        s_hc[pid*16 + 8 + k] = noise[(cnt-1)*NZ + k];
    }
    __syncthreads();

    // decoder LSTM step 0: ctx = out = 0 -> e = relu(b_dec), c_in = 0
    int k = k16;
    float h = s_hc[pid*16 + k];
    float g0 = s_bP[k], g1 = s_bP[16+k], g2 = s_bP[32+k], g3 = s_bP[48+k];
    #pragma unroll
    for (int d = 0; d < HD; d++) {
        float ev = s_e0[d];
        float hv = __shfl(h, d, 16);
        g0 += s_wihP[(k)*17+d]*ev    + s_whhP[(k)*17+d]*hv;
        g1 += s_wihP[(16+k)*17+d]*ev + s_whhP[(16+k)*17+d]*hv;
        g2 += s_wihP[(32+k)*17+d]*ev + s_whhP[(32+k)*17+d]*hv;
        g3 += s_wihP[(48+k)*17+d]*ev + s_whhP[(48+k)*17+d]*hv;
    }
    float c = sigm(g0)*tanh_f(g2);       // c_in = 0
    float hn = sigm(g3)*tanh_f(c);
    ws[WS_H + n*HD + k] = hn;
    ws[WS_C + n*HD + k] = c;

    float hb0=0.f, hb1=0.f, hb2=0.f, hb3=0.f;
    #pragma unroll
    for (int d = 0; d < HD; d++) {
        float hv = __shfl(hn, d, 16);
        hb0 += s_wm1h[(k)*17+d]*hv;    hb1 += s_wm1h[(16+k)*17+d]*hv;
        hb2 += s_wm1h[(32+k)*17+d]*hv; hb3 += s_wm1h[(48+k)*17+d]*hv;
    }
    float* hb = ws + WS_HB0 + n*64;
    hb[k] = hb0; hb[16+k] = hb1; hb[32+k] = hb2; hb[48+k] = hb3;
    if (k < 2) ws[WS_POS0 + n*2 + k] = obs_pos[((OBS-1)*NPED+n)*2 + k];
}

// one (i,j) pair: returns attention score s, fills pre[4] (relu'd m2 output)
__device__ __forceinline__ float pool_pair(
        int j, float pix, float piy,
        const float* s_posx, const float* s_posy,
        const float4* s_abb, const float4* s_wm2t,
        const float4* s_bm24, const float4* s_watt4, float batt,
        const float* hbbuf, float4 pre[4])
{
    float cx = pix - s_posx[j], cy = piy - s_posy[j];
    pre[0] = s_bm24[0]; pre[1] = s_bm24[1]; pre[2] = s_bm24[2]; pre[3] = s_bm24[3];
    const float4* HB4 = (const float4*)(hbbuf + j*64);
    #pragma unroll
    for (int uq = 0; uq < 16; uq++) {
        float4 hb = HB4[uq];
        #define DO_U(q_, comp_) { \
            float4 ab = s_abb[uq*4+q_]; \
            float h1 = fmaxf(ab.z + ab.x*cx + ab.y*cy + (comp_), 0.f); \
            const float4* wr = s_wm2t + (uq*4+q_)*4; \
            fma4(pre[0], wr[0], h1); fma4(pre[1], wr[1], h1); \
            fma4(pre[2], wr[2], h1); fma4(pre[3], wr[3], h1); }
        DO_U(0, hb.x) DO_U(1, hb.y) DO_U(2, hb.z) DO_U(3, hb.w)
        #undef DO_U
    }
    float s = batt;
    #pragma unroll
    for (int q = 0; q < 4; q++) {
        float4 v = pre[q];
        v.x = fmaxf(v.x,0.f); v.y = fmaxf(v.y,0.f); v.z = fmaxf(v.z,0.f); v.w = fmaxf(v.w,0.f);
        float4 wa = s_watt4[q];
        s += wa.x*v.x + wa.y*v.y + wa.z*v.z + wa.w*v.w;
        pre[q] = v;
    }
    return s;
}

// ---------- per decoder step: pool(t) -> out(t) -> pos(t) -> LSTM(t+1) ------
__global__ __launch_bounds__(256) void pool_step_kernel(
        int t, int last, const int* nei,
        fp Wse, fp bse, fp Wm1, fp bm1, fp Wm2, fp bm2, fp Watt, fp batt,
        fp Wdec, fp bdec, fp Wihp, fp Whhp, fp bihp, fp bhhp, fp Wout, fp bout,
        float* ws, float* dout)
{
    __shared__ float4 s_abb[64], s_wm2t[256], s_bm24[4], s_watt4[4];
    __shared__ float s_batt;
    __shared__ float s_posx[NPED], s_posy[NPED];
    __shared__ int   s_list[NPED], s_cnt[8];
    __shared__ float s_red[4*17], s_mred[4], s_ctx[16];
    __shared__ float s_wdec[16*19], s_bdec[16], s_wout[32], s_bout[2];
    __shared__ float s_wihP[64*17], s_whhP[64*17], s_wm1h[64*17], s_bP[64];
    int tid = threadIdx.x;

    if (tid < 64) {   // fold W_se/b_se into W_m1 -> A0,A1,bb per unit u
        float a0 = 0.f, a1 = 0.f, bb = bm1[tid];
        for (int kk = 0; kk < 16; kk++) {
            float w = Wm1[tid*32 + kk];
            a0 += w*Wse[kk*2+0]; a1 += w*Wse[kk*2+1]; bb += w*bse[kk];
        }
        s_abb[tid] = make_float4(a0, a1, bb, 0.f);
    }
    for (int i = tid; i < 1024; i += 256) {
        int u = i >> 4, v = i & 15;
        ((float*)s_wm2t)[u*16 + v] = Wm2[v*64 + u];
    }
    if (tid < 16) { ((float*)s_bm24)[tid] = bm2[tid]; ((float*)s_watt4)[tid] = Watt[tid]; }
    if (tid == 0) s_batt = batt[0];
    for (int i = tid; i < 288; i += 256) s_wdec[(i/18)*19 + (i%18)] = Wdec[i];
    if (tid < 16) s_bdec[tid] = bdec[tid];
    if (tid < 32) s_wout[tid] = Wout[tid];
    if (tid < 2)  s_bout[tid] = bout[tid];
    if (!last) {
        for (int i = tid; i < 1024; i += 256) {
            int r = i>>4, d = i&15;
            s_wihP[r*17+d] = Wihp[i];
            s_whhP[r*17+d] = Whhp[i];
            s_wm1h[r*17+d] = Wm1[r*32 + 16 + d];
        }
        if (tid < 64) s_bP[tid] = bihp[tid] + bhhp[tid];
    }
    const float* posrd = ws + ((t & 1) ? WS_POS1 : WS_POS0);
    const float* hbrd  = ws + ((t & 1) ? WS_HB1  : WS_HB0 );
    float* poswr = ws + ((t & 1) ? WS_POS0 : WS_POS1);
    float* hbwr  = ws + ((t & 1) ? WS_HB0  : WS_HB1 );
    {
        const float2* p2 = (const float2*)posrd;
        for (int j = tid; j < NPED; j += 256) { float2 pp = p2[j]; s_posx[j] = pp.x; s_posy[j] = pp.y; }
    }
    __syncthreads();

    int i = blockIdx.x;
    int w = tid >> 6, lane = tid & 63;
    unsigned long long below = (1ull << lane) - 1ull;

    // active-neighbor compaction
    const int* neirow = nei + ((size_t)t*NPED + i)*NPED;
    int a0 = neirow[tid]       > 0;
    int a1 = neirow[256 + tid] > 0;
    unsigned long long m0 = __ballot(a0), m1 = __ballot(a1);
    if (lane == 0) { s_cnt[w] = __popcll(m0); s_cnt[4+w] = __popcll(m1); }
    __syncthreads();
    int cnt = 0, base0 = 0, base1 = 0;
    #pragma unroll
    for (int q = 0; q < 8; q++) {
        int cq = s_cnt[q];
        cnt += cq;
        if (q < w)     base0 += cq;
        if (q < 4 + w) base1 += cq;
    }
    if (a0) s_list[base0 + __popcll(m0 & below)] = tid;
    if (a1) s_list[base1 + __popcll(m1 & below)] = 256 + tid;
    __syncthreads();

    float pix = s_posx[i], piy = s_posy[i];
    float4 z = make_float4(0.f,0.f,0.f,0.f);
    float4 preA[4] = {z,z,z,z}, preB[4] = {z,z,z,z};
    float sA = -INFINITY, sB = -INFINITY;
    if (tid < cnt)
        sA = pool_pair(s_list[tid], pix, piy, s_posx, s_posy,
                       s_abb, s_wm2t, s_bm24, s_watt4, s_batt, hbrd, preA);
    if (256 + tid < cnt)
        sB = pool_pair(s_list[256+tid], pix, piy, s_posx, s_posy,
                       s_abb, s_wm2t, s_bm24, s_watt4, s_batt, hbrd, preB);

    // pass 1: global max
    float mloc = fmaxf(sA, sB);
    #pragma unroll
    for (int off = 32; off >= 1; off >>= 1) mloc = fmaxf(mloc, __shfl_xor(mloc, off));
    if (lane == 0) s_mred[w] = mloc;
    __syncthreads();
    float M = fmaxf(fmaxf(s_mred[0], s_mred[1]), fmaxf(s_mred[2], s_mred[3]));

    // pass 2: rescaled sums
    if (cnt > 0) {
        float wA = __expf(sA - M), wB = __expf(sB - M);
        float l = wA + wB;
        float accv[16];
        const float* pa = (const float*)preA;
        const float* pb = (const float*)preB;
        #pragma unroll
        for (int v = 0; v < 16; v++) accv[v] = wA*pa[v] + wB*pb[v];
        #pragma unroll
        for (int off = 32; off >= 1; off >>= 1) {
            l += __shfl_xor(l, off);
            #pragma unroll
            for (int v = 0; v < 16; v++) accv[v] += __shfl_xor(accv[v], off);
        }
        if (lane == 0) {
            s_red[w*17] = l;
            #pragma unroll
            for (int v = 0; v < 16; v++) s_red[w*17 + 1 + v] = accv[v];
        }
    }
    __syncthreads();
    if (tid < 16) {
        float cv = 0.f;
        if (cnt > 0) {
            float L = s_red[0] + s_red[17] + s_red[34] + s_red[51];
            float a = s_red[1+tid] + s_red[17+1+tid] + s_red[34+1+tid] + s_red[51+1+tid];
            cv = (L > 0.f) ? a / L : 0.f;
        }
        s_ctx[tid] = cv;
    }
    __syncthreads();

    // ------- out(t), pos(t), LSTM(t+1), HB(t+1): lanes 0..15 -------
    if (tid < 16) {
        int k = tid;
        float ctx = s_ctx[k];
        float h = ws[WS_H + i*HD + k];
        float ch = ctx + h;
        float r0 = s_wout[k]*ch, r1 = s_wout[16+k]*ch;
        #pragma unroll
        for (int off = 8; off >= 1; off >>= 1) {
            r0 += __shfl_xor(r0, off, 16);
            r1 += __shfl_xor(r1, off, 16);
        }
        float o0 = tanh_f(s_bout[0] + r0)*4.4f;
        float o1 = tanh_f(s_bout[1] + r1)*4.4f;
        if (k == 0) { dout[(t*NPED + i)*2 + 0] = o0; poswr[i*2+0] = pix + o0; }
        if (k == 1) { dout[(t*NPED + i)*2 + 1] = o1; poswr[i*2+1] = piy + o1; }
        if (!last) {
            float e = s_bdec[k];
            #pragma unroll
            for (int d = 0; d < HD; d++) e += s_wdec[k*19 + d]*s_ctx[d];
            e += s_wdec[k*19+16]*o0 + s_wdec[k*19+17]*o1;
            e = fmaxf(e, 0.f);
            float c = ws[WS_C + i*HD + k];
            float g0 = s_bP[k], g1 = s_bP[16+k], g2 = s_bP[32+k], g3 = s_bP[48+k];
            #pragma unroll
            for (int d = 0; d < HD; d++) {
                float ev = __shfl(e, d, 16);
                float hv = __shfl(h, d, 16);
                g0 += s_wihP[(k)*17+d]*ev    + s_whhP[(k)*17+d]*hv;
                g1 += s_wihP[(16+k)*17+d]*ev + s_whhP[(16+k)*17+d]*hv;
                g2 += s_wihP[(32+k)*17+d]*ev + s_whhP[(32+k)*17+d]*hv;
                g3 += s_wihP[(48+k)*17+d]*ev + s_whhP[(48+k)*17+d]*hv;
            }
            c = sigm(g1)*c + sigm(g0)*tanh_f(g2);
            float hn = sigm(g3)*tanh_f(c);
            ws[WS_H + i*HD + k] = hn;
            ws[WS_C + i*HD + k] = c;
            float hb0=0.f, hb1=0.f, hb2=0.f, hb3=0.f;
            #pragma unroll
            for (int d = 0; d < HD; d++) {
                float hv = __shfl(hn, d, 16);
                hb0 += s_wm1h[(k)*17+d]*hv;    hb1 += s_wm1h[(16+k)*17+d]*hv;
                hb2 += s_wm1h[(32+k)*17+d]*hv; hb3 += s_wm1h[(48+k)*17+d]*hv;
            }
            float* hb = hbwr + i*64;
            hb[k] = hb0; hb[16+k] = hb1; hb[32+k] = hb2; hb[48+k] = hb3;
        }
    }
}

extern "C" void kernel_launch(void* const* d_in, const int* in_sizes, int n_in,
                              void* d_out, int out_size, void* d_ws, size_t ws_size,
                              hipStream_t stream)
{
    fp traj = (fp)d_in[0];
    fp obs  = (fp)d_in[1];
    fp h0   = (fp)d_in[3];
    fp c0   = (fp)d_in[4];
    fp noise= (fp)d_in[5];
    fp Wenc = (fp)d_in[6];  fp benc = (fp)d_in[7];
    fp Wdec = (fp)d_in[8];  fp bdec = (fp)d_in[9];
    fp Wiht = (fp)d_in[10]; fp Whht = (fp)d_in[11];
    fp biht = (fp)d_in[12]; fp bhht = (fp)d_in[13];
    fp Wihp = (fp)d_in[14]; fp Whhp = (fp)d_in[15];
    fp bihp = (fp)d_in[16]; fp bhhp = (fp)d_in[17];
    fp Wout = (fp)d_in[18]; fp bout = (fp)d_in[19];
    fp Wse  = (fp)d_in[20]; fp bse  = (fp)d_in[21];
    fp Wm1  = (fp)d_in[22]; fp bm1  = (fp)d_in[23];
    fp Wm2  = (fp)d_in[24]; fp bm2  = (fp)d_in[25];
    fp Watt = (fp)d_in[26]; fp batt = (fp)d_in[27];
    const int* sse = (const int*)d_in[28];
    const int* nei = (const int*)d_in[29];
    float* ws = (float*)d_ws;
    float* out = (float*)d_out;

    hipLaunchKernelGGL(init_kernel, dim3(32), dim3(256), 0, stream,
                       traj, obs, h0, c0, noise, Wenc, benc, Wiht, Whht, biht, bhht,
                       bdec, Wihp, Whhp, bihp, bhhp, Wm1, sse, ws);
    for (int t = 0; t < PRED; t++) {
        hipLaunchKernelGGL(pool_step_kernel, dim3(NPED), dim3(256), 0, stream,
                           t, (t == PRED-1) ? 1 : 0, nei,
                           Wse, bse, Wm1, bm1, Wm2, bm2, Watt, batt,
                           Wdec, bdec, Wihp, Whhp, bihp, bhhp, Wout, bout,
                           ws, out);
    }
}

// Round 7
// 258.530 us; speedup vs baseline: 2.8592x; 1.1287x over previous
//
#include <hip/hip_runtime.h>
#include <math.h>

#define NPED 512
#define OBS 8
#define PRED 12
#define HE 8
#define HD 16
#define EMB 16
#define NZ 8
#define NSEQ 8

typedef const float* fp;

__device__ __forceinline__ float frcp(float x){ return __builtin_amdgcn_rcpf(x); }
__device__ __forceinline__ float sigm(float x){ return frcp(1.0f + __expf(-x)); }
__device__ __forceinline__ float tanh_f(float x){ return 1.0f - 2.0f*frcp(__expf(2.0f*x) + 1.0f); }
__device__ __forceinline__ void fma4(float4& a, const float4 w, float s){
    a.x += w.x*s; a.y += w.y*s; a.z += w.z*s; a.w += w.w*s;
}
__device__ __forceinline__ float dot4(const float4 a, float x, float y, float z, float w2){
    return a.x*x + a.y*y + a.z*z + a.w*w2;
}

// ws layout (floats). h,c: block-private slots. pos,HB: parity double-buffered.
#define WS_H    0
#define WS_C    (WS_H + NPED*HD)
#define WS_POS0 (WS_C + NPED*HD)
#define WS_POS1 (WS_POS0 + NPED*2)
#define WS_HB0  (WS_POS1 + NPED*2)
#define WS_HB1  (WS_HB0 + NPED*64)

// ---------- init: encoder (8 lanes/ped) + decoder LSTM step 0 (16 lanes/ped)
__global__ __launch_bounds__(256) void init_kernel(
        fp traj, fp obs_pos, fp h0, fp c0, fp noise,
        fp Wenc, fp benc, fp Wih, fp Whh, fp bih, fp bhh,
        fp bdec, fp Wihp, fp Whhp, fp bihp, fp bhhp, fp Wm1,
        const int* sse, float* ws)
{
    __shared__ float s_wenc[32], s_benc[16], s_wihT[32*17], s_whhT[32*9], s_bT[32];
    __shared__ float s_wihP[64*17], s_whhP[64*17], s_wm1h[64*17], s_bP[64], s_e0[16];
    __shared__ float s_hc[16*16];
    int tid = threadIdx.x;
    if (tid < 32) { s_wenc[tid] = Wenc[tid]; s_bT[tid] = bih[tid] + bhh[tid]; }
    if (tid < 16) { s_benc[tid] = benc[tid]; s_e0[tid] = fmaxf(bdec[tid], 0.f); }
    for (int i = tid; i < 512; i += 256) s_wihT[(i>>4)*17 + (i&15)] = Wih[i];
    { int i = tid; if (i < 256) s_whhT[(i>>3)*9 + (i&7)] = Whh[i]; }
    for (int i = tid; i < 1024; i += 256) {
        int r = i>>4, d = i&15;
        s_wihP[r*17+d] = Wihp[i];
        s_whhP[r*17+d] = Whhp[i];
        s_wm1h[r*17+d] = Wm1[r*32 + 16 + d];
    }
    if (tid < 64) s_bP[tid] = bihp[tid] + bhhp[tid];
    __syncthreads();

    int pid = tid >> 4, k16 = tid & 15;
    int n = blockIdx.x*16 + pid;

    if (k16 < 8) {                       // encoder, 8 lanes per ped
        int k = k16;
        float h = h0[n*HE+k], c = c0[n*HE+k];
        for (int t = 0; t < OBS; t++) {
            float x0 = traj[(t*NPED+n)*2+0];
            float x1 = traj[(t*NPED+n)*2+1];
            float g0 = s_bT[k], g1 = s_bT[8+k], g2 = s_bT[16+k], g3 = s_bT[24+k];
            #pragma unroll
            for (int d = 0; d < EMB; d++) {
                float e = fmaxf(s_wenc[d*2]*x0 + s_wenc[d*2+1]*x1 + s_benc[d], 0.f);
                g0 += s_wihT[(k)*17+d]*e;    g1 += s_wihT[(8+k)*17+d]*e;
                g2 += s_wihT[(16+k)*17+d]*e; g3 += s_wihT[(24+k)*17+d]*e;
            }
            #pragma unroll
            for (int d = 0; d < HE; d++) {
                float hv = __shfl(h, d, 8);
                g0 += s_whhT[(k)*9+d]*hv;    g1 += s_whhT[(8+k)*9+d]*hv;
                g2 += s_whhT[(16+k)*9+d]*hv; g3 += s_whhT[(24+k)*9+d]*hv;
            }
            c = sigm(g1)*c + sigm(g0)*tanh_f(g2);
            h = sigm(g3)*tanh_f(c);
        }
        int cnt = 0;
        #pragma unroll
        for (int s2 = 0; s2 < NSEQ; s2++) cnt += (sse[s2*2] <= n) ? 1 : 0;
        s_hc[pid*16 + k]     = h;
        s_hc[pid*16 + 8 + k] = noise[(cnt-1)*NZ + k];
    }
    __syncthreads();

    // decoder LSTM step 0: ctx = out = 0 -> e = relu(b_dec), c_in = 0
    int k = k16;
    float h = s_hc[pid*16 + k];
    float g0 = s_bP[k], g1 = s_bP[16+k], g2 = s_bP[32+k], g3 = s_bP[48+k];
    #pragma unroll
    for (int d = 0; d < HD; d++) {
        float ev = s_e0[d];
        float hv = __shfl(h, d, 16);
        g0 += s_wihP[(k)*17+d]*ev    + s_whhP[(k)*17+d]*hv;
        g1 += s_wihP[(16+k)*17+d]*ev + s_whhP[(16+k)*17+d]*hv;
        g2 += s_wihP[(32+k)*17+d]*ev + s_whhP[(32+k)*17+d]*hv;
        g3 += s_wihP[(48+k)*17+d]*ev + s_whhP[(48+k)*17+d]*hv;
    }
    float c = sigm(g0)*tanh_f(g2);       // c_in = 0
    float hn = sigm(g3)*tanh_f(c);
    ws[WS_H + n*HD + k] = hn;
    ws[WS_C + n*HD + k] = c;

    float hb0=0.f, hb1=0.f, hb2=0.f, hb3=0.f;
    #pragma unroll
    for (int d = 0; d < HD; d++) {
        float hv = __shfl(hn, d, 16);
        hb0 += s_wm1h[(k)*17+d]*hv;    hb1 += s_wm1h[(16+k)*17+d]*hv;
        hb2 += s_wm1h[(32+k)*17+d]*hv; hb3 += s_wm1h[(48+k)*17+d]*hv;
    }
    float* hb = ws + WS_HB0 + n*64;
    hb[k] = hb0; hb[16+k] = hb1; hb[32+k] = hb2; hb[48+k] = hb3;
    if (k < 2) ws[WS_POS0 + n*2 + k] = obs_pos[((OBS-1)*NPED+n)*2 + k];
}

// ---------- per decoder step: pool(t) -> out(t) -> pos(t) -> LSTM(t+1) ------
// 512 threads/block, one neighbor slot per thread; epilogue on wave 0.
__global__ __launch_bounds__(512, 4) void pool_step_kernel(
        int t, int last, const int* nei,
        fp Wse, fp bse, fp Wm1, fp bm1, fp Wm2, fp bm2, fp Watt, fp batt,
        fp Wdec, fp bdec, fp Wihp, fp Whhp, fp bihp, fp bhhp, fp Wout, fp bout,
        float* ws, float* dout)
{
    __shared__ float4 s_abb[64], s_wm2t[256], s_bm24[4], s_watt4[4];
    __shared__ float s_batt;
    __shared__ float s_posx[NPED], s_posy[NPED];
    __shared__ int   s_list[NPED], s_cnt[8];
    __shared__ float s_red[8*17], s_mred[8], s_ctx[16];
    __shared__ float s_wdec[16*19], s_bdec[16], s_wout[32], s_bout[2];
    int tid = threadIdx.x;

    if (tid < 64) {   // fold W_se/b_se into W_m1 -> A0,A1,bb per unit u
        float a0 = 0.f, a1 = 0.f, bb = bm1[tid];
        for (int kk = 0; kk < 16; kk++) {
            float w = Wm1[tid*32 + kk];
            a0 += w*Wse[kk*2+0]; a1 += w*Wse[kk*2+1]; bb += w*bse[kk];
        }
        s_abb[tid] = make_float4(a0, a1, bb, 0.f);
    }
    for (int i = tid; i < 1024; i += 512) {
        int u = i >> 4, v = i & 15;
        ((float*)s_wm2t)[u*16 + v] = Wm2[v*64 + u];
    }
    if (tid < 16) { ((float*)s_bm24)[tid] = bm2[tid]; ((float*)s_watt4)[tid] = Watt[tid]; }
    if (tid == 0) s_batt = batt[0];
    for (int i = tid; i < 288; i += 512) s_wdec[(i/18)*19 + (i%18)] = Wdec[i];
    if (tid < 16) s_bdec[tid] = bdec[tid];
    if (tid < 32) s_wout[tid] = Wout[tid];
    if (tid < 2)  s_bout[tid] = bout[tid];

    const float* posrd = ws + ((t & 1) ? WS_POS1 : WS_POS0);
    const float* hbrd  = ws + ((t & 1) ? WS_HB1  : WS_HB0 );
    float* poswr = ws + ((t & 1) ? WS_POS0 : WS_POS1);
    float* hbwr  = ws + ((t & 1) ? WS_HB0  : WS_HB1 );
    {
        const float2* p2 = (const float2*)posrd;
        for (int j = tid; j < NPED; j += 512) { float2 pp = p2[j]; s_posx[j] = pp.x; s_posy[j] = pp.y; }
    }
    __syncthreads();

    int i = blockIdx.x;
    int w = tid >> 6, lane = tid & 63;
    unsigned long long below = (1ull << lane) - 1ull;

    // active-neighbor compaction (one slot per thread)
    int a = nei[((size_t)t*NPED + i)*NPED + tid] > 0;
    unsigned long long mb = __ballot(a);
    if (lane == 0) s_cnt[w] = __popcll(mb);
    __syncthreads();
    int cnt = 0, base = 0;
    #pragma unroll
    for (int q = 0; q < 8; q++) {
        int cq = s_cnt[q];
        cnt += cq;
        if (q < w) base += cq;
    }
    if (a) s_list[base + __popcll(mb & below)] = tid;
    __syncthreads();

    float pix = s_posx[i], piy = s_posy[i];
    float4 z = make_float4(0.f,0.f,0.f,0.f);
    float4 pre[4] = {z,z,z,z};
    float sc = -INFINITY;
    if (tid < cnt) {
        int j = s_list[tid];
        float cx = pix - s_posx[j], cy = piy - s_posy[j];
        pre[0] = s_bm24[0]; pre[1] = s_bm24[1]; pre[2] = s_bm24[2]; pre[3] = s_bm24[3];
        const float4* HB4 = (const float4*)(hbrd + j*64);
        #pragma unroll
        for (int uq = 0; uq < 16; uq++) {
            float4 hb = HB4[uq];
            #define DO_U(q_, comp_) { \
                float4 ab = s_abb[uq*4+q_]; \
                float h1 = fmaxf(ab.z + ab.x*cx + ab.y*cy + (comp_), 0.f); \
                const float4* wr = s_wm2t + (uq*4+q_)*4; \
                fma4(pre[0], wr[0], h1); fma4(pre[1], wr[1], h1); \
                fma4(pre[2], wr[2], h1); fma4(pre[3], wr[3], h1); }
            DO_U(0, hb.x) DO_U(1, hb.y) DO_U(2, hb.z) DO_U(3, hb.w)
            #undef DO_U
        }
        sc = s_batt;
        #pragma unroll
        for (int q = 0; q < 4; q++) {
            float4 v = pre[q];
            v.x = fmaxf(v.x,0.f); v.y = fmaxf(v.y,0.f); v.z = fmaxf(v.z,0.f); v.w = fmaxf(v.w,0.f);
            float4 wa = s_watt4[q];
            sc += dot4(wa, v.x, v.y, v.z, v.w);
            pre[q] = v;
        }
    }

    // pass 1: global max
    float mloc = sc;
    #pragma unroll
    for (int off = 32; off >= 1; off >>= 1) mloc = fmaxf(mloc, __shfl_xor(mloc, off));
    if (lane == 0) s_mred[w] = mloc;
    __syncthreads();
    float M = s_mred[0];
    #pragma unroll
    for (int q = 1; q < 8; q++) M = fmaxf(M, s_mred[q]);

    // pass 2: rescaled sums (inactive lanes: sc = -inf -> weight 0)
    if (cnt > 0) {
        float wexp = __expf(sc - M);
        float l = wexp;
        float accv[16];
        const float* pa = (const float*)pre;
        #pragma unroll
        for (int v = 0; v < 16; v++) accv[v] = wexp*pa[v];
        #pragma unroll
        for (int off = 32; off >= 1; off >>= 1) {
            l += __shfl_xor(l, off);
            #pragma unroll
            for (int v = 0; v < 16; v++) accv[v] += __shfl_xor(accv[v], off);
        }
        if (lane == 0) {
            s_red[w*17] = l;
            #pragma unroll
            for (int v = 0; v < 16; v++) s_red[w*17 + 1 + v] = accv[v];
        }
    }
    __syncthreads();
    if (tid < 16) {
        float cv = 0.f;
        if (cnt > 0) {
            float L = 0.f, acc = 0.f;
            #pragma unroll
            for (int q = 0; q < 8; q++) { L += s_red[q*17]; acc += s_red[q*17 + 1 + tid]; }
            cv = (L > 0.f) ? acc / L : 0.f;
        }
        s_ctx[tid] = cv;
    }
    __syncthreads();

    // ------- epilogue on wave 0: out(t), pos(t), LSTM(t+1), HB(t+1) -------
    if (tid < 64) {
        int r = tid;                       // gate row / HB row
        float h16 = 0.f, ctx16 = 0.f, cst = 0.f;
        if (r < 16) {
            h16   = ws[WS_H + i*HD + r];
            ctx16 = s_ctx[r];
            cst   = ws[WS_C + i*HD + r];
        }
        // out head (lanes 0..15)
        float ch = ctx16 + h16;
        float r0 = 0.f, r1 = 0.f;
        if (r < 16) { r0 = s_wout[r]*ch; r1 = s_wout[16+r]*ch; }
        #pragma unroll
        for (int off = 8; off >= 1; off >>= 1) {
            r0 += __shfl_xor(r0, off, 16);
            r1 += __shfl_xor(r1, off, 16);
        }
        float o0 = tanh_f(s_bout[0] + r0)*4.4f;
        float o1 = tanh_f(s_bout[1] + r1)*4.4f;
        if (r == 0) { dout[(t*NPED + i)*2 + 0] = o0; poswr[i*2+0] = pix + o0; }
        if (r == 1) { dout[(t*NPED + i)*2 + 1] = o1; poswr[i*2+1] = piy + o1; }

        if (!last) {
            // e (lanes 0..15)
            float e = 0.f;
            if (r < 16) {
                e = s_bdec[r];
                #pragma unroll
                for (int d = 0; d < HD; d++) e += s_wdec[r*19 + d]*s_ctx[d];
                e += s_wdec[r*19+16]*o0 + s_wdec[r*19+17]*o1;
                e = fmaxf(e, 0.f);
            }
            // gates: one row per lane, weights direct from L2
            const float4* wi4 = (const float4*)(Wihp + r*16);
            const float4* wh4 = (const float4*)(Whhp + r*16);
            float4 wi0 = wi4[0], wi1 = wi4[1], wi2 = wi4[2], wi3 = wi4[3];
            float4 wh0 = wh4[0], wh1 = wh4[1], wh2 = wh4[2], wh3 = wh4[3];
            float g = bihp[r] + bhhp[r];
            #define GD(q_, wiv, whv, d0) { \
                g += wiv.x*__shfl(e, d0)   + whv.x*__shfl(h16, d0); \
                g += wiv.y*__shfl(e, d0+1) + whv.y*__shfl(h16, d0+1); \
                g += wiv.z*__shfl(e, d0+2) + whv.z*__shfl(h16, d0+2); \
                g += wiv.w*__shfl(e, d0+3) + whv.w*__shfl(h16, d0+3); }
            GD(0, wi0, wh0, 0) GD(1, wi1, wh1, 4) GD(2, wi2, wh2, 8) GD(3, wi3, wh3, 12)
            #undef GD
            // nonlinearity on lanes 0..15
            float gi = __shfl(g, r & 15);
            float gf = __shfl(g, 16 + (r & 15));
            float gg = __shfl(g, 32 + (r & 15));
            float go = __shfl(g, 48 + (r & 15));
            float hn = 0.f;
            if (r < 16) {
                float cn = sigm(gf)*cst + sigm(gi)*tanh_f(gg);
                hn = sigm(go)*tanh_f(cn);
                ws[WS_H + i*HD + r] = hn;
                ws[WS_C + i*HD + r] = cn;
            }
            // HB row per lane
            const float4* wm4 = (const float4*)(Wm1 + r*32 + 16);
            float4 m0 = wm4[0], m1 = wm4[1], m2 = wm4[2], m3 = wm4[3];
            float hb = 0.f;
            #define HD4(mv, d0) { \
                hb += mv.x*__shfl(hn, d0)   + mv.y*__shfl(hn, d0+1); \
                hb += mv.z*__shfl(hn, d0+2) + mv.w*__shfl(hn, d0+3); }
            HD4(m0, 0) HD4(m1, 4) HD4(m2, 8) HD4(m3, 12)
            #undef HD4
            hbwr[i*64 + r] = hb;
        }
    }
}

extern "C" void kernel_launch(void* const* d_in, const int* in_sizes, int n_in,
                              void* d_out, int out_size, void* d_ws, size_t ws_size,
                              hipStream_t stream)
{
    fp traj = (fp)d_in[0];
    fp obs  = (fp)d_in[1];
    fp h0   = (fp)d_in[3];
    fp c0   = (fp)d_in[4];
    fp noise= (fp)d_in[5];
    fp Wenc = (fp)d_in[6];  fp benc = (fp)d_in[7];
    fp Wdec = (fp)d_in[8];  fp bdec = (fp)d_in[9];
    fp Wiht = (fp)d_in[10]; fp Whht = (fp)d_in[11];
    fp biht = (fp)d_in[12]; fp bhht = (fp)d_in[13];
    fp Wihp = (fp)d_in[14]; fp Whhp = (fp)d_in[15];
    fp bihp = (fp)d_in[16]; fp bhhp = (fp)d_in[17];
    fp Wout = (fp)d_in[18]; fp bout = (fp)d_in[19];
    fp Wse  = (fp)d_in[20]; fp bse  = (fp)d_in[21];
    fp Wm1  = (fp)d_in[22]; fp bm1  = (fp)d_in[23];
    fp Wm2  = (fp)d_in[24]; fp bm2  = (fp)d_in[25];
    fp Watt = (fp)d_in[26]; fp batt = (fp)d_in[27];
    const int* sse = (const int*)d_in[28];
    const int* nei = (const int*)d_in[29];
    float* ws = (float*)d_ws;
    float* out = (float*)d_out;

    hipLaunchKernelGGL(init_kernel, dim3(32), dim3(256), 0, stream,
                       traj, obs, h0, c0, noise, Wenc, benc, Wiht, Whht, biht, bhht,
                       bdec, Wihp, Whhp, bihp, bhhp, Wm1, sse, ws);
    for (int t = 0; t < PRED; t++) {
        hipLaunchKernelGGL(pool_step_kernel, dim3(NPED), dim3(512), 0, stream,
                           t, (t == PRED-1) ? 1 : 0, nei,
                           Wse, bse, Wm1, bm1, Wm2, bm2, Watt, batt,
                           Wdec, bdec, Wihp, Whhp, bihp, bhhp, Wout, bout,
                           ws, out);
    }
}

// Round 8
// 169.710 us; speedup vs baseline: 4.3555x; 1.5234x over previous
//
#include <hip/hip_runtime.h>
#include <math.h>

#define NPED 512
#define OBS 8
#define PRED 12
#define HE 8
#define HD 16
#define EMB 16
#define NZ 8
#define NSEQ 8

typedef const float* fp;
typedef float f2 __attribute__((ext_vector_type(2)));

__device__ __forceinline__ float frcp(float x){ return __builtin_amdgcn_rcpf(x); }
__device__ __forceinline__ float sigm(float x){ return frcp(1.0f + __expf(-x)); }
__device__ __forceinline__ float tanh_f(float x){ return 1.0f - 2.0f*frcp(__expf(2.0f*x) + 1.0f); }

// ws layout (floats). h,c: block-private slots. pos,HB: parity double-buffered.
// A0/A1/BB: folded W_se->W_m1 (precomputed in init). WM2T: u-major transposed Wm2.
#define WS_H    0
#define WS_C    (WS_H + NPED*HD)
#define WS_POS0 (WS_C + NPED*HD)
#define WS_POS1 (WS_POS0 + NPED*2)
#define WS_HB0  (WS_POS1 + NPED*2)
#define WS_HB1  (WS_HB0 + NPED*64)
#define WS_A0   (WS_HB1 + NPED*64)
#define WS_A1   (WS_A0 + 64)
#define WS_BB   (WS_A1 + 64)
#define WS_WM2T (WS_BB + 64)     // 1024 floats

// ---------- init: encoder + decoder LSTM step 0 + pool-constant precompute --
__global__ __launch_bounds__(256) void init_kernel(
        fp traj, fp obs_pos, fp h0, fp c0, fp noise,
        fp Wenc, fp benc, fp Wih, fp Whh, fp bih, fp bhh,
        fp bdec, fp Wihp, fp Whhp, fp bihp, fp bhhp, fp Wm1,
        fp Wse, fp bse, fp bm1, fp Wm2,
        const int* sse, float* ws)
{
    __shared__ float s_wenc[32], s_benc[16], s_wihT[32*17], s_whhT[32*9], s_bT[32];
    __shared__ float s_wihP[64*17], s_whhP[64*17], s_wm1h[64*17], s_bP[64], s_e0[16];
    __shared__ float s_hc[16*16];
    int tid = threadIdx.x;

    if (blockIdx.x == 0) {   // pool constants -> ws
        if (tid < 64) {
            float a0 = 0.f, a1 = 0.f, bb = bm1[tid];
            for (int kk = 0; kk < 16; kk++) {
                float w = Wm1[tid*32 + kk];
                a0 += w*Wse[kk*2+0]; a1 += w*Wse[kk*2+1]; bb += w*bse[kk];
            }
            ws[WS_A0 + tid] = a0; ws[WS_A1 + tid] = a1; ws[WS_BB + tid] = bb;
        }
        for (int i = tid; i < 1024; i += 256) {
            int u = i >> 4, v = i & 15;
            ws[WS_WM2T + u*16 + v] = Wm2[v*64 + u];
        }
    }

    if (tid < 32) { s_wenc[tid] = Wenc[tid]; s_bT[tid] = bih[tid] + bhh[tid]; }
    if (tid < 16) { s_benc[tid] = benc[tid]; s_e0[tid] = fmaxf(bdec[tid], 0.f); }
    for (int i = tid; i < 512; i += 256) s_wihT[(i>>4)*17 + (i&15)] = Wih[i];
    { int i = tid; if (i < 256) s_whhT[(i>>3)*9 + (i&7)] = Whh[i]; }
    for (int i = tid; i < 1024; i += 256) {
        int r = i>>4, d = i&15;
        s_wihP[r*17+d] = Wihp[i];
        s_whhP[r*17+d] = Whhp[i];
        s_wm1h[r*17+d] = Wm1[r*32 + 16 + d];
    }
    if (tid < 64) s_bP[tid] = bihp[tid] + bhhp[tid];
    __syncthreads();

    int pid = tid >> 4, k16 = tid & 15;
    int n = blockIdx.x*16 + pid;

    if (k16 < 8) {                       // encoder, 8 lanes per ped
        int k = k16;
        float h = h0[n*HE+k], c = c0[n*HE+k];
        for (int t = 0; t < OBS; t++) {
            float x0 = traj[(t*NPED+n)*2+0];
            float x1 = traj[(t*NPED+n)*2+1];
            float g0 = s_bT[k], g1 = s_bT[8+k], g2 = s_bT[16+k], g3 = s_bT[24+k];
            #pragma unroll
            for (int d = 0; d < EMB; d++) {
                float e = fmaxf(s_wenc[d*2]*x0 + s_wenc[d*2+1]*x1 + s_benc[d], 0.f);
                g0 += s_wihT[(k)*17+d]*e;    g1 += s_wihT[(8+k)*17+d]*e;
                g2 += s_wihT[(16+k)*17+d]*e; g3 += s_wihT[(24+k)*17+d]*e;
            }
            #pragma unroll
            for (int d = 0; d < HE; d++) {
                float hv = __shfl(h, d, 8);
                g0 += s_whhT[(k)*9+d]*hv;    g1 += s_whhT[(8+k)*9+d]*hv;
                g2 += s_whhT[(16+k)*9+d]*hv; g3 += s_whhT[(24+k)*9+d]*hv;
            }
            c = sigm(g1)*c + sigm(g0)*tanh_f(g2);
            h = sigm(g3)*tanh_f(c);
        }
        int cnt = 0;
        #pragma unroll
        for (int s2 = 0; s2 < NSEQ; s2++) cnt += (sse[s2*2] <= n) ? 1 : 0;
        s_hc[pid*16 + k]     = h;
        s_hc[pid*16 + 8 + k] = noise[(cnt-1)*NZ + k];
    }
    __syncthreads();

    // decoder LSTM step 0: ctx = out = 0 -> e = relu(b_dec), c_in = 0
    int k = k16;
    float h = s_hc[pid*16 + k];
    float g0 = s_bP[k], g1 = s_bP[16+k], g2 = s_bP[32+k], g3 = s_bP[48+k];
    #pragma unroll
    for (int d = 0; d < HD; d++) {
        float ev = s_e0[d];
        float hv = __shfl(h, d, 16);
        g0 += s_wihP[(k)*17+d]*ev    + s_whhP[(k)*17+d]*hv;
        g1 += s_wihP[(16+k)*17+d]*ev + s_whhP[(16+k)*17+d]*hv;
        g2 += s_wihP[(32+k)*17+d]*ev + s_whhP[(32+k)*17+d]*hv;
        g3 += s_wihP[(48+k)*17+d]*ev + s_whhP[(48+k)*17+d]*hv;
    }
    float c = sigm(g0)*tanh_f(g2);       // c_in = 0
    float hn = sigm(g3)*tanh_f(c);
    ws[WS_H + n*HD + k] = hn;
    ws[WS_C + n*HD + k] = c;

    float hb0=0.f, hb1=0.f, hb2=0.f, hb3=0.f;
    #pragma unroll
    for (int d = 0; d < HD; d++) {
        float hv = __shfl(hn, d, 16);
        hb0 += s_wm1h[(k)*17+d]*hv;    hb1 += s_wm1h[(16+k)*17+d]*hv;
        hb2 += s_wm1h[(32+k)*17+d]*hv; hb3 += s_wm1h[(48+k)*17+d]*hv;
    }
    float* hb = ws + WS_HB0 + n*64;
    hb[k] = hb0; hb[16+k] = hb1; hb[32+k] = hb2; hb[48+k] = hb3;
    if (k < 2) ws[WS_POS0 + n*2 + k] = obs_pos[((OBS-1)*NPED+n)*2 + k];
}

// ---------- per decoder step: pool(t) -> out(t) -> pos(t) -> LSTM(t+1) ------
__global__ __launch_bounds__(512, 4) void pool_step_kernel(
        int t, int last, const int* nei,
        fp Wm1, fp bm2, fp Watt, fp batt,
        fp Wdec, fp bdec, fp Wihp, fp Whhp, fp bihp, fp bhhp, fp Wout, fp bout,
        float* ws, float* dout)
{
    __shared__ float s_A0[64], s_A1[64], s_BB[64];
    __shared__ float s_wm2t[1024];
    __shared__ float s_bm2[16], s_watt[16];
    __shared__ float s_batt;
    __shared__ float s_posx[NPED], s_posy[NPED];
    __shared__ int   s_list[NPED], s_cnt[8];
    __shared__ float s_mat[16*512];
    __shared__ float s_lred[8], s_mred[8], s_ctxacc[16], s_ctx[16];
    __shared__ float s_wdec[16*19], s_bdec[16], s_wout[32], s_bout[2];
    int tid = threadIdx.x;

    if (tid < 64) { s_A0[tid] = ws[WS_A0+tid]; s_A1[tid] = ws[WS_A1+tid]; s_BB[tid] = ws[WS_BB+tid]; }
    if (tid < 256) ((float4*)s_wm2t)[tid] = ((const float4*)(ws + WS_WM2T))[tid];
    if (tid < 16) { s_bm2[tid] = bm2[tid]; s_watt[tid] = Watt[tid]; }
    if (tid == 0) s_batt = batt[0];
    for (int i = tid; i < 288; i += 512) s_wdec[(i/18)*19 + (i%18)] = Wdec[i];
    if (tid < 16) s_bdec[tid] = bdec[tid];
    if (tid < 32) s_wout[tid] = Wout[tid];
    if (tid < 2)  s_bout[tid] = bout[tid];

    const float* posrd = ws + ((t & 1) ? WS_POS1 : WS_POS0);
    const float* hbrd  = ws + ((t & 1) ? WS_HB1  : WS_HB0 );
    float* poswr = ws + ((t & 1) ? WS_POS0 : WS_POS1);
    float* hbwr  = ws + ((t & 1) ? WS_HB0  : WS_HB1 );
    {
        const float2* p2 = (const float2*)posrd;
        for (int j = tid; j < NPED; j += 512) { float2 pp = p2[j]; s_posx[j] = pp.x; s_posy[j] = pp.y; }
    }
    __syncthreads();

    int i = blockIdx.x;
    int w = tid >> 6, lane = tid & 63;
    unsigned long long below = (1ull << lane) - 1ull;

    // active-neighbor compaction (one slot per thread)
    int a = nei[((size_t)t*NPED + i)*NPED + tid] > 0;
    unsigned long long mb = __ballot(a);
    if (lane == 0) s_cnt[w] = __popcll(mb);
    __syncthreads();
    int cnt = 0, base = 0;
    #pragma unroll
    for (int q = 0; q < 8; q++) {
        int cq = s_cnt[q];
        cnt += cq;
        if (q < w) base += cq;
    }
    if (a) s_list[base + __popcll(mb & below)] = tid;
    __syncthreads();

    float pix = s_posx[i], piy = s_posy[i];
    f2 pre2[8];
    #pragma unroll
    for (int q = 0; q < 8; q++) pre2[q] = (f2){0.f, 0.f};
    float sc = -INFINITY;

    if (tid < cnt) {
        #pragma unroll
        for (int q = 0; q < 8; q++) pre2[q] = (f2){s_bm2[2*q], s_bm2[2*q+1]};
        int j = s_list[tid];
        float cx = pix - s_posx[j], cy = piy - s_posy[j];
        const float4* HB4 = (const float4*)(hbrd + j*64);
        const f2* A0v = (const f2*)s_A0;
        const f2* A1v = (const f2*)s_A1;
        const f2* BBv = (const f2*)s_BB;
        #pragma unroll
        for (int uq = 0; uq < 16; uq++) {
            float4 hb = HB4[uq];
            f2 hA = {hb.x, hb.y}, hB = {hb.z, hb.w};
            f2 h1A = __builtin_elementwise_max(A0v[2*uq]*cx + A1v[2*uq]*cy + (BBv[2*uq] + hA), (f2){0.f,0.f});
            f2 h1B = __builtin_elementwise_max(A0v[2*uq+1]*cx + A1v[2*uq+1]*cy + (BBv[2*uq+1] + hB), (f2){0.f,0.f});
            #define ACC16(u_, hsc_) { \
                f2 hs = {hsc_, hsc_}; \
                const f2* wr = (const f2*)(s_wm2t + (u_)*16); \
                for (int q = 0; q < 8; q++) pre2[q] = __builtin_elementwise_fma(wr[q], hs, pre2[q]); }
            ACC16(uq*4+0, h1A.x) ACC16(uq*4+1, h1A.y) ACC16(uq*4+2, h1B.x) ACC16(uq*4+3, h1B.y)
            #undef ACC16
        }
        f2 sacc = {0.f, 0.f};
        const f2* wa = (const f2*)s_watt;
        #pragma unroll
        for (int q = 0; q < 8; q++) {
            pre2[q] = __builtin_elementwise_max(pre2[q], (f2){0.f,0.f});
            sacc = __builtin_elementwise_fma(pre2[q], wa[q], sacc);
        }
        sc = s_batt + sacc.x + sacc.y;
    }

    // pass 1: global max of scores
    float mloc = sc;
    #pragma unroll
    for (int off = 32; off >= 1; off >>= 1) mloc = fmaxf(mloc, __shfl_xor(mloc, off));
    if (lane == 0) s_mred[w] = mloc;
    __syncthreads();
    float M = s_mred[0];
    #pragma unroll
    for (int q = 1; q < 8; q++) M = fmaxf(M, s_mred[q]);

    // pass 2: weights; l via small butterfly, acc via LDS transpose reduce
    float wexp = (tid < cnt) ? __expf(sc - M) : 0.f;
    float l = wexp;
    #pragma unroll
    for (int off = 32; off >= 1; off >>= 1) l += __shfl_xor(l, off);
    if (lane == 0) s_lred[w] = l;
    {
        const float* pa = (const float*)pre2;
        #pragma unroll
        for (int v = 0; v < 16; v++) s_mat[v*512 + tid] = wexp * pa[v];
    }
    __syncthreads();
    {
        int vv = tid >> 5, cc = tid & 31;
        float ssum = 0.f;
        #pragma unroll
        for (int e = 0; e < 16; e++) ssum += s_mat[vv*512 + cc + e*32];
        #pragma unroll
        for (int off = 16; off >= 1; off >>= 1) ssum += __shfl_xor(ssum, off, 32);
        if (cc == 0) s_ctxacc[vv] = ssum;
    }
    __syncthreads();
    if (tid < 16) {
        float cv = 0.f;
        if (cnt > 0) {
            float L = 0.f;
            #pragma unroll
            for (int q = 0; q < 8; q++) L += s_lred[q];
            cv = (L > 0.f) ? s_ctxacc[tid] / L : 0.f;
        }
        s_ctx[tid] = cv;
    }
    __syncthreads();

    // ------- epilogue on wave 0: out(t), pos(t), LSTM(t+1), HB(t+1) -------
    if (tid < 64) {
        int r = tid;                       // gate row / HB row
        float h16 = 0.f, ctx16 = 0.f, cst = 0.f;
        if (r < 16) {
            h16   = ws[WS_H + i*HD + r];
            ctx16 = s_ctx[r];
            cst   = ws[WS_C + i*HD + r];
        }
        // out head (lanes 0..15)
        float ch = ctx16 + h16;
        float r0 = 0.f, r1 = 0.f;
        if (r < 16) { r0 = s_wout[r]*ch; r1 = s_wout[16+r]*ch; }
        #pragma unroll
        for (int off = 8; off >= 1; off >>= 1) {
            r0 += __shfl_xor(r0, off, 16);
            r1 += __shfl_xor(r1, off, 16);
        }
        float o0 = tanh_f(s_bout[0] + r0)*4.4f;
        float o1 = tanh_f(s_bout[1] + r1)*4.4f;
        if (r == 0) { dout[(t*NPED + i)*2 + 0] = o0; poswr[i*2+0] = pix + o0; }
        if (r == 1) { dout[(t*NPED + i)*2 + 1] = o1; poswr[i*2+1] = piy + o1; }

        if (!last) {
            // e (lanes 0..15)
            float e = 0.f;
            if (r < 16) {
                e = s_bdec[r];
                #pragma unroll
                for (int d = 0; d < HD; d++) e += s_wdec[r*19 + d]*s_ctx[d];
                e += s_wdec[r*19+16]*o0 + s_wdec[r*19+17]*o1;
                e = fmaxf(e, 0.f);
            }
            // gates: one row per lane, weights direct from L2
            const float4* wi4 = (const float4*)(Wihp + r*16);
            const float4* wh4 = (const float4*)(Whhp + r*16);
            float4 wi0 = wi4[0], wi1 = wi4[1], wi2 = wi4[2], wi3 = wi4[3];
            float4 wh0 = wh4[0], wh1 = wh4[1], wh2 = wh4[2], wh3 = wh4[3];
            float g = bihp[r] + bhhp[r];
            #define GD(wiv, whv, d0) { \
                g += wiv.x*__shfl(e, d0)   + whv.x*__shfl(h16, d0); \
                g += wiv.y*__shfl(e, d0+1) + whv.y*__shfl(h16, d0+1); \
                g += wiv.z*__shfl(e, d0+2) + whv.z*__shfl(h16, d0+2); \
                g += wiv.w*__shfl(e, d0+3) + whv.w*__shfl(h16, d0+3); }
            GD(wi0, wh0, 0) GD(wi1, wh1, 4) GD(wi2, wh2, 8) GD(wi3, wh3, 12)
            #undef GD
            // nonlinearity on lanes 0..15
            float gi = __shfl(g, r & 15);
            float gf = __shfl(g, 16 + (r & 15));
            float gg = __shfl(g, 32 + (r & 15));
            float go = __shfl(g, 48 + (r & 15));
            float hn = 0.f;
            if (r < 16) {
                float cn = sigm(gf)*cst + sigm(gi)*tanh_f(gg);
                hn = sigm(go)*tanh_f(cn);
                ws[WS_H + i*HD + r] = hn;
                ws[WS_C + i*HD + r] = cn;
            }
            // HB row per lane
            const float4* wm4 = (const float4*)(Wm1 + r*32 + 16);
            float4 m0 = wm4[0], m1 = wm4[1], m2 = wm4[2], m3 = wm4[3];
            float hb = 0.f;
            #define HBD(mv, d0) { \
                hb += mv.x*__shfl(hn, d0)   + mv.y*__shfl(hn, d0+1); \
                hb += mv.z*__shfl(hn, d0+2) + mv.w*__shfl(hn, d0+3); }
            HBD(m0, 0) HBD(m1, 4) HBD(m2, 8) HBD(m3, 12)
            #undef HBD
            hbwr[i*64 + r] = hb;
        }
    }
}

extern "C" void kernel_launch(void* const* d_in, const int* in_sizes, int n_in,
                              void* d_out, int out_size, void* d_ws, size_t ws_size,
                              hipStream_t stream)
{
    fp traj = (fp)d_in[0];
    fp obs  = (fp)d_in[1];
    fp h0   = (fp)d_in[3];
    fp c0   = (fp)d_in[4];
    fp noise= (fp)d_in[5];
    fp Wenc = (fp)d_in[6];  fp benc = (fp)d_in[7];
    fp Wdec = (fp)d_in[8];  fp bdec = (fp)d_in[9];
    fp Wiht = (fp)d_in[10]; fp Whht = (fp)d_in[11];
    fp biht = (fp)d_in[12]; fp bhht = (fp)d_in[13];
    fp Wihp = (fp)d_in[14]; fp Whhp = (fp)d_in[15];
    fp bihp = (fp)d_in[16]; fp bhhp = (fp)d_in[17];
    fp Wout = (fp)d_in[18]; fp bout = (fp)d_in[19];
    fp Wse  = (fp)d_in[20]; fp bse  = (fp)d_in[21];
    fp Wm1  = (fp)d_in[22]; fp bm1  = (fp)d_in[23];
    fp Wm2  = (fp)d_in[24]; fp bm2  = (fp)d_in[25];
    fp Watt = (fp)d_in[26]; fp batt = (fp)d_in[27];
    const int* sse = (const int*)d_in[28];
    const int* nei = (const int*)d_in[29];
    float* ws = (float*)d_ws;
    float* out = (float*)d_out;

    hipLaunchKernelGGL(init_kernel, dim3(32), dim3(256), 0, stream,
                       traj, obs, h0, c0, noise, Wenc, benc, Wiht, Whht, biht, bhht,
                       bdec, Wihp, Whhp, bihp, bhhp, Wm1, Wse, bse, bm1, Wm2, sse, ws);
    for (int t = 0; t < PRED; t++) {
        hipLaunchKernelGGL(pool_step_kernel, dim3(NPED), dim3(512), 0, stream,
                           t, (t == PRED-1) ? 1 : 0, nei,
                           Wm1, bm2, Watt, batt,
                           Wdec, bdec, Wihp, Whhp, bihp, bhhp, Wout, bout,
                           ws, out);
    }
}